// Round 15
// baseline (310.841 us; speedup 1.0000x reference)
//
#include <hip/hip_runtime.h>

#define NN 100000
#define NE 1600000
#define FD 128
#define CO 10
#define BN_EPS 1e-5f
#define NBUK 782                               // buckets of 128 nodes
#define NBUKP 784
#define BCAP 3072
#define SEGE 8192
#define NSEG 196                               // ceil(NE/SEGE)
#define H3P 16                                 // padded H3s stride (64 B lines)
#define RPAD 68                                // LDS row stride in u32 (272 B)

typedef __attribute__((ext_vector_type(8))) short short8;
typedef __attribute__((ext_vector_type(4))) float f32x4;

__device__ __forceinline__ unsigned short f2bf(float f) {
  unsigned int u = __builtin_bit_cast(unsigned int, f);
  u = (u + 0x7FFFu + ((u >> 16) & 1u)) >> 16;
  return (unsigned short)u;
}
__device__ __forceinline__ float bf2f(unsigned short h) {
  unsigned int u = ((unsigned int)h) << 16;
  return __builtin_bit_cast(float, u);
}
__device__ __forceinline__ float blo(unsigned int u) {
  return __builtin_bit_cast(float, u << 16);
}
__device__ __forceinline__ float bhi(unsigned int u) {
  return __builtin_bit_cast(float, u & 0xFFFF0000u);
}
__device__ __forceinline__ unsigned int cvt_pk_bf16(float a, float b) {
  unsigned int r;
  asm("v_cvt_pk_bf16_f32 %0, %1, %2" : "=v"(r) : "v"(a), "v"(b));
  return r;
}

// ---------------- fused: per-segment histogram + W-convert + BN constants ----
__global__ __launch_bounds__(256) void k_hist_prep(
    const int* __restrict__ dst, int* __restrict__ histM,
    const float* __restrict__ W1, const float* __restrict__ W2,
    unsigned short* __restrict__ w1hi, unsigned short* __restrict__ w1lo,
    unsigned short* __restrict__ w2hi, unsigned short* __restrict__ w2lo,
    const float* __restrict__ b1, const float* __restrict__ g1,
    const float* __restrict__ be1, const float* __restrict__ m1,
    const float* __restrict__ v1,
    const float* __restrict__ b2, const float* __restrict__ g2,
    const float* __restrict__ be2, const float* __restrict__ m2,
    const float* __restrict__ v2,
    float* __restrict__ sc1, float* __restrict__ sh1,
    float* __restrict__ sc2, float* __restrict__ sh2) {
  __shared__ int hist[NBUK];
  int b = blockIdx.x, t = threadIdx.x;
  if (b < NSEG) {
    for (int i = t; i < NBUK; i += 256) hist[i] = 0;
    __syncthreads();
    int e0 = b * SEGE, e1 = min(e0 + SEGE, NE);
    for (int e = e0 + t; e < e1; e += 256) atomicAdd(&hist[dst[e] >> 7], 1);
    __syncthreads();
    for (int i = t; i < NBUK; i += 256) histM[b * NBUKP + i] = hist[i];
  } else if (b < NSEG + 128) {
    int bb = b - NSEG;
    const float* W = (bb < 64) ? W1 : W2;
    unsigned short* whi = (bb < 64) ? w1hi : w2hi;
    unsigned short* wlo = (bb < 64) ? w1lo : w2lo;
    int i = (bb & 63) * 256 + t;
    int k = i >> 7, n = i & 127;
    float w = W[i];
    unsigned short h = f2bf(w);
    unsigned short l = f2bf(w - bf2f(h));
    int idx = ((((k >> 5) * 8) + (n >> 4)) * 64 + ((k >> 3) & 3) * 16 + (n & 15)) * 8 + (k & 7);
    whi[idx] = h;
    wlo[idx] = l;
  } else {
    if (t < FD) {
      float s = g1[t] * rsqrtf(v1[t] + BN_EPS);
      sc1[t] = s;
      sh1[t] = (b1[t] - m1[t]) * s + be1[t];
    } else if (t < 2 * FD) {
      int f = t - FD;
      float s = g2[f] * rsqrtf(v2[f] + BN_EPS);
      sc2[f] = s;
      sh2[f] = (b2[f] - m2[f]) * s + be2[f];
    }
  }
}

// ---------------- per-bucket prefix over segments ----------------
__global__ __launch_bounds__(256) void k_colscan(const int* __restrict__ histM,
                                                 int* __restrict__ segbase,
                                                 int* __restrict__ btot) {
  __shared__ int lds[256];
  int b = blockIdx.x, t = threadIdx.x;
  int v = (t < NSEG) ? histM[t * NBUKP + b] : 0;
  lds[t] = v;
  __syncthreads();
  int mine = v;
  for (int off = 1; off < 256; off <<= 1) {
    int add = (t >= off) ? lds[t - off] : 0;
    __syncthreads();
    lds[t] += add;
    __syncthreads();
  }
  if (t < NSEG) segbase[t * NBUKP + b] = lds[t] - mine;
  if (t == 255) btot[b] = lds[255];
}

// ---------------- scatter into buckets, LDS cursors, packed u32 -------------
__global__ __launch_bounds__(256) void k_scatter2(const int* __restrict__ src,
                                                  const int* __restrict__ dst,
                                                  const int* __restrict__ segbase,
                                                  unsigned int* __restrict__ buck) {
  __shared__ int base[NBUK];
  int b = blockIdx.x, t = threadIdx.x;
  for (int i = t; i < NBUK; i += 256) base[i] = segbase[b * NBUKP + i];
  __syncthreads();
  int e0 = b * SEGE, e1 = min(e0 + SEGE, NE);
  for (int e = e0 + t; e < e1; e += 256) {
    int s = src[e], d = dst[e];
    int bk = d >> 7;
    int slot = atomicAdd(&base[bk], 1);
    buck[(size_t)bk * BCAP + slot] = ((unsigned int)(d & 127) << 17) | (unsigned int)s;
  }
}

// ---------------- finalize: count + local scan + nrange + place -------------
__global__ __launch_bounds__(256) void k_finalize(const int* __restrict__ btot,
                                                  const unsigned int* __restrict__ buck,
                                                  uint4* __restrict__ nrange,
                                                  int* __restrict__ csr_src) {
  __shared__ unsigned int ebuf[BCAP];  // 12 KB
  __shared__ int cnt[128];
  __shared__ int xoff[128];
  int b = blockIdx.x, t = threadIdx.x;
  int nb = btot[b];
  const unsigned int* bp = buck + (size_t)b * BCAP;
  for (int i = t; i < nb; i += 256) ebuf[i] = bp[i];
  if (t < 128) cnt[t] = 0;
  __syncthreads();
  for (int i = t; i < nb; i += 256) atomicAdd(&cnt[ebuf[i] >> 17], 1);
  __syncthreads();
  if (t < 128) xoff[t] = cnt[t];
  __syncthreads();
  for (int off = 1; off < 128; off <<= 1) {
    int add = 0;
    if (t < 128 && t >= off) add = xoff[t - off];
    __syncthreads();
    if (t < 128) xoff[t] += add;
    __syncthreads();
  }
  if (t < 128) {
    int node = b * 128 + t;
    int ex = xoff[t] - cnt[t];
    if (node < NN) {
      uint4 nr;
      nr.x = (unsigned)(b * BCAP + ex);
      nr.y = (unsigned)cnt[t];
      nr.z = __builtin_bit_cast(unsigned int, rsqrtf((float)cnt[t] + 1.0f));
      nr.w = 0;
      nrange[node] = nr;
    }
    xoff[t] = ex;
    cnt[t] = 0;
  }
  __syncthreads();
  int base = b * BCAP;
  for (int i = t; i < nb; i += 256) {
    unsigned int p = ebuf[i];
    int dl = (int)(p >> 17);
    int l = atomicAdd(&cnt[dl], 1);
    csr_src[base + xoff[dl] + l] = (int)(p & 0x1FFFFu);
  }
}

// ---------------- layer-1 MFMA GEMM (f32 A, bf16x3) -> pre-scaled bf16 rows --
__global__ __launch_bounds__(256) void k_gemm128_mfma(const float* __restrict__ X,
                                                      const unsigned short* __restrict__ whi,
                                                      const unsigned short* __restrict__ wlo,
                                                      const uint4* __restrict__ nrange,
                                                      unsigned short* __restrict__ Hbs,
                                                      int nrows) {
  int tid = threadIdx.x;
  int lane = tid & 63, wv = tid >> 6;
  int lg = lane >> 4, li = lane & 15;
  int wr0 = blockIdx.x * 64 + wv * 16;
  int row = wr0 + li;
  bool ok = row < nrows;

  short8 ahi[4], alo[4];
#pragma unroll
  for (int ks = 0; ks < 4; ++ks) {
    if (ok) {
      const float* xp = X + (unsigned)(row * FD + ks * 32 + lg * 8);
      float4 v0 = *(const float4*)xp;
      float4 v1 = *(const float4*)(xp + 4);
      float f[8] = {v0.x, v0.y, v0.z, v0.w, v1.x, v1.y, v1.z, v1.w};
      unsigned int hp[4], lp[4];
#pragma unroll
      for (int j = 0; j < 4; ++j) {
        float a = f[2 * j], c = f[2 * j + 1];
        hp[j] = cvt_pk_bf16(a, c);
        float ra = a - blo(hp[j]);
        float rc = c - bhi(hp[j]);
        lp[j] = cvt_pk_bf16(ra, rc);
      }
      uint4 hv = {hp[0], hp[1], hp[2], hp[3]};
      uint4 lv = {lp[0], lp[1], lp[2], lp[3]};
      ahi[ks] = __builtin_bit_cast(short8, hv);
      alo[ks] = __builtin_bit_cast(short8, lv);
    } else {
#pragma unroll
      for (int j = 0; j < 8; ++j) { ahi[ks][j] = 0; alo[ks][j] = 0; }
    }
  }

  int rb = wr0 + lg * 4;
  float dvr[4];
#pragma unroll
  for (int r = 0; r < 4; ++r)
    dvr[r] = (rb + r < nrows) ? __builtin_bit_cast(float, nrange[rb + r].z) : 0.f;

#pragma unroll
  for (int nt = 0; nt < 8; ++nt) {
    f32x4 acc = {0.f, 0.f, 0.f, 0.f};
#pragma unroll
    for (int ks = 0; ks < 4; ++ks) {
      unsigned int bidx = (unsigned)(((ks * 8 + nt) * 64 + lane) * 8);
      short8 bh = *(const short8*)&whi[bidx];
      short8 bl = *(const short8*)&wlo[bidx];
      acc = __builtin_amdgcn_mfma_f32_16x16x32_bf16(ahi[ks], bh, acc, 0, 0, 0);
      acc = __builtin_amdgcn_mfma_f32_16x16x32_bf16(alo[ks], bh, acc, 0, 0, 0);
      acc = __builtin_amdgcn_mfma_f32_16x16x32_bf16(ahi[ks], bl, acc, 0, 0, 0);
    }
    int col = nt * 16 + li;   // C/D: col=lane&15, row=(lane>>4)*4+reg [m89]
#pragma unroll
    for (int r = 0; r < 4; ++r) {
      if (rb + r < nrows)
        Hbs[(unsigned)((rb + r) * FD + col)] = f2bf(acc[r] * dvr[r]);
    }
  }
}

// ---------------- FUSED: layer-1 gather + BN + layer-2 GEMM -----------------
// Wave-private: gather 16 nodes -> bf16 rows in LDS -> 16x128 MFMA -> Hbs2.
__global__ __launch_bounds__(256) void k_gather_gemm(const uint4* __restrict__ nrange,
                                                     const int* __restrict__ csr_src,
                                                     const unsigned short* __restrict__ Hbs,
                                                     const float* __restrict__ sc,
                                                     const float* __restrict__ sh,
                                                     const unsigned short* __restrict__ whi,
                                                     const unsigned short* __restrict__ wlo,
                                                     unsigned short* __restrict__ Hbs2) {
  __shared__ unsigned int rows[4][16][RPAD];   // 17.4 KB, 272 B/row
  int tid = threadIdx.x;
  int lane = tid & 63, wv = tid >> 6;
  int lg = lane >> 4, li = lane & 15;
  int n0 = blockIdx.x * 64 + wv * 16;
  const unsigned int* Hc = (const unsigned int*)Hbs;
  float scx = sc[lane * 2], scy = sc[lane * 2 + 1];
  float shx = sh[lane * 2], shy = sh[lane * 2 + 1];

  // phase A: gather 16 nodes (wave-private)
  for (int r16 = 0; r16 < 16; ++r16) {
    int node = __builtin_amdgcn_readfirstlane(n0 + r16);
    unsigned int uo = 0;
    if (node < NN) {
      uint4 nr = nrange[node];
      int beg = (int)nr.x, end = (int)(nr.x + nr.y);
      float dv = __builtin_bit_cast(float, nr.z);
      float px0, px1 = 0.f, px2 = 0.f, px3 = 0.f;
      float py0, py1 = 0.f, py2 = 0.f, py3 = 0.f;
      {
        unsigned int us = Hc[(unsigned)(node * 64) + lane];
        px0 = blo(us); py0 = bhi(us);
      }
      int e = beg;
      for (; e + 3 < end; e += 4) {
        unsigned int u0 = Hc[((unsigned)csr_src[e + 0] << 6) + lane];
        unsigned int u1 = Hc[((unsigned)csr_src[e + 1] << 6) + lane];
        unsigned int u2 = Hc[((unsigned)csr_src[e + 2] << 6) + lane];
        unsigned int u3 = Hc[((unsigned)csr_src[e + 3] << 6) + lane];
        px0 += blo(u0); py0 += bhi(u0);
        px1 += blo(u1); py1 += bhi(u1);
        px2 += blo(u2); py2 += bhi(u2);
        px3 += blo(u3); py3 += bhi(u3);
      }
      for (; e < end; ++e) {
        unsigned int u0 = Hc[((unsigned)csr_src[e] << 6) + lane];
        px0 += blo(u0); py0 += bhi(u0);
      }
      float accx = ((px0 + px1) + (px2 + px3)) * dv;
      float accy = ((py0 + py1) + (py2 + py3)) * dv;
      accx = fmaxf(fmaf(accx, scx, shx), 0.f);
      accy = fmaxf(fmaf(accy, scy, shy), 0.f);
      uo = cvt_pk_bf16(accx, accy);
    }
    rows[wv][r16][lane] = uo;
  }

  // phase B: 16x128 @ 128x128 bf16 GEMM from LDS (wave-private, no barrier)
  short8 ahi[4];
  {
    const unsigned int* rp = &rows[wv][li][0];
#pragma unroll
    for (int ks = 0; ks < 4; ++ks) {
      uint4 q = *(const uint4*)(rp + ks * 16 + lg * 4);
      ahi[ks] = __builtin_bit_cast(short8, q);
    }
  }
  int rb = n0 + lg * 4;
  float dvr[4];
#pragma unroll
  for (int r = 0; r < 4; ++r)
    dvr[r] = (rb + r < NN) ? __builtin_bit_cast(float, nrange[rb + r].z) : 0.f;

#pragma unroll
  for (int nt = 0; nt < 8; ++nt) {
    f32x4 acc = {0.f, 0.f, 0.f, 0.f};
#pragma unroll
    for (int ks = 0; ks < 4; ++ks) {
      unsigned int bidx = (unsigned)(((ks * 8 + nt) * 64 + lane) * 8);
      short8 bh = *(const short8*)&whi[bidx];
      short8 bl = *(const short8*)&wlo[bidx];
      acc = __builtin_amdgcn_mfma_f32_16x16x32_bf16(ahi[ks], bh, acc, 0, 0, 0);
      acc = __builtin_amdgcn_mfma_f32_16x16x32_bf16(ahi[ks], bl, acc, 0, 0, 0);
    }
    int col = nt * 16 + li;
#pragma unroll
    for (int r = 0; r < 4; ++r) {
      if (rb + r < NN)
        Hbs2[(unsigned)((rb + r) * FD + col)] = f2bf(acc[r] * dvr[r]);
    }
  }
}

// ---------------- layer-2 gather + BN + fused W3 GEMM -> pre-scaled H3s -----
__global__ __launch_bounds__(256) void k_gather128_out(const uint4* __restrict__ nrange,
                                                       const int* __restrict__ csr_src,
                                                       const unsigned short* __restrict__ Hbs,
                                                       const float* __restrict__ sc,
                                                       const float* __restrict__ sh,
                                                       const float* __restrict__ W3,
                                                       float* __restrict__ H3s) {
  int node = blockIdx.x * 4 + (threadIdx.x >> 6);
  node = __builtin_amdgcn_readfirstlane(node);
  int lane = threadIdx.x & 63;
  float w3r[20];
  {
    const float* wp = W3 + lane * 2 * CO;
#pragma unroll
    for (int j = 0; j < 20; ++j) w3r[j] = wp[j];
  }
  const unsigned int* Hc = (const unsigned int*)Hbs;
  uint4 nr = nrange[node];
  int beg = (int)nr.x, end = (int)(nr.x + nr.y);
  float dv = __builtin_bit_cast(float, nr.z);
  float px0, px1 = 0.f, px2 = 0.f, px3 = 0.f;
  float py0, py1 = 0.f, py2 = 0.f, py3 = 0.f;
  {
    unsigned int us = Hc[(unsigned)(node * 64) + lane];
    px0 = blo(us); py0 = bhi(us);
  }
  int e = beg;
  for (; e + 3 < end; e += 4) {
    unsigned int u0 = Hc[((unsigned)csr_src[e + 0] << 6) + lane];
    unsigned int u1 = Hc[((unsigned)csr_src[e + 1] << 6) + lane];
    unsigned int u2 = Hc[((unsigned)csr_src[e + 2] << 6) + lane];
    unsigned int u3 = Hc[((unsigned)csr_src[e + 3] << 6) + lane];
    px0 += blo(u0); py0 += bhi(u0);
    px1 += blo(u1); py1 += bhi(u1);
    px2 += blo(u2); py2 += bhi(u2);
    px3 += blo(u3); py3 += bhi(u3);
  }
  for (; e < end; ++e) {
    unsigned int u0 = Hc[((unsigned)csr_src[e] << 6) + lane];
    px0 += blo(u0); py0 += bhi(u0);
  }
  float accx = ((px0 + px1) + (px2 + px3)) * dv;
  float accy = ((py0 + py1) + (py2 + py3)) * dv;
  float scx = sc[lane * 2], scy = sc[lane * 2 + 1];
  float shx = sh[lane * 2], shy = sh[lane * 2 + 1];
  accx = fmaxf(fmaf(accx, scx, shx), 0.f);
  accy = fmaxf(fmaf(accy, scy, shy), 0.f);
  float p[10];
#pragma unroll
  for (int c = 0; c < CO; ++c) p[c] = fmaf(accx, w3r[c], accy * w3r[10 + c]);
#pragma unroll
  for (int off = 32; off >= 1; off >>= 1) {
#pragma unroll
    for (int c = 0; c < CO; ++c) p[c] += __shfl_xor(p[c], off);
  }
#pragma unroll
  for (int c = 0; c < CO; ++c)
    if (lane == c) H3s[(unsigned)(node * H3P + c)] = p[c] * dv;
}

// ---------------- gather 10 feat over pre-scaled H3s (stride 16) ------------
__global__ __launch_bounds__(256) void k_gather10(const uint4* __restrict__ nrange,
                                                  const int* __restrict__ csr_src,
                                                  const float* __restrict__ H3s,
                                                  const float* __restrict__ b3,
                                                  float* __restrict__ out) {
  int node = blockIdx.x * 16 + (threadIdx.x >> 4);
  if (node >= NN) return;
  int c = threadIdx.x & 15;
  uint4 nr = nrange[node];
  int beg = (int)nr.x, end = (int)(nr.x + nr.y);
  float dv = __builtin_bit_cast(float, nr.z);
  float acc = 0.f;
  if (c < CO) acc = H3s[(unsigned)(node * H3P + c)];
  for (int e = beg; e < end; ++e) {
    int s = csr_src[e];
    if (c < CO) acc += H3s[(unsigned)(s * H3P + c)];
  }
  if (c < CO) out[(unsigned)(node * CO + c)] = fmaf(acc, dv, b3[c]);
}

// ---------------- launch ----------------
extern "C" void kernel_launch(void* const* d_in, const int* in_sizes, int n_in,
                              void* d_out, int out_size, void* d_ws, size_t ws_size,
                              hipStream_t stream) {
  const float* x = (const float*)d_in[0];
  const int* src = (const int*)d_in[1];
  const int* dst = (const int*)d_in[2];
  const float* W1 = (const float*)d_in[3];
  const float* b1 = (const float*)d_in[4];
  const float* g1 = (const float*)d_in[5];
  const float* be1 = (const float*)d_in[6];
  const float* m1 = (const float*)d_in[7];
  const float* v1 = (const float*)d_in[8];
  const float* W2 = (const float*)d_in[9];
  const float* b2 = (const float*)d_in[10];
  const float* g2 = (const float*)d_in[11];
  const float* be2 = (const float*)d_in[12];
  const float* m2 = (const float*)d_in[13];
  const float* v2 = (const float*)d_in[14];
  const float* W3 = (const float*)d_in[15];
  const float* b3 = (const float*)d_in[16];
  float* out = (float*)d_out;

  char* wsb = (char*)d_ws;
  int* histM = (int*)wsb;                      wsb += (size_t)NSEG * NBUKP * 4;
  int* segbase = (int*)wsb;                    wsb += (size_t)NSEG * NBUKP * 4;
  int* btot = (int*)wsb;                       wsb += NBUKP * 4;
  uint4* nrange = (uint4*)wsb;                 wsb += (size_t)NN * 16;
  float* sc1 = (float*)wsb;                    wsb += FD * 4;
  float* sh1 = (float*)wsb;                    wsb += FD * 4;
  float* sc2 = (float*)wsb;                    wsb += FD * 4;
  float* sh2 = (float*)wsb;                    wsb += FD * 4;
  unsigned short* w1hi = (unsigned short*)wsb; wsb += FD * FD * 2;
  unsigned short* w1lo = (unsigned short*)wsb; wsb += FD * FD * 2;
  unsigned short* w2hi = (unsigned short*)wsb; wsb += FD * FD * 2;
  unsigned short* w2lo = (unsigned short*)wsb; wsb += FD * FD * 2;
  int* csr_src = (int*)wsb;                    wsb += (size_t)NBUK * BCAP * 4;
  unsigned int* buck = (unsigned int*)wsb;     wsb += (size_t)NBUK * BCAP * 4;
  unsigned short* Hbs1 = (unsigned short*)wsb; wsb += (size_t)NN * FD * 2;
  unsigned short* Hbs2 = (unsigned short*)wsb; wsb += (size_t)NN * FD * 2;
  float* H3s = (float*)wsb;                    wsb += (size_t)NN * H3P * 4;

  k_hist_prep<<<NSEG + 129, 256, 0, stream>>>(dst, histM, W1, W2,
                                              w1hi, w1lo, w2hi, w2lo,
                                              b1, g1, be1, m1, v1,
                                              b2, g2, be2, m2, v2,
                                              sc1, sh1, sc2, sh2);
  k_colscan<<<NBUK, 256, 0, stream>>>(histM, segbase, btot);
  k_scatter2<<<NSEG, 256, 0, stream>>>(src, dst, segbase, buck);
  k_finalize<<<NBUK, 256, 0, stream>>>(btot, buck, nrange, csr_src);

  int gemm_blocks = (NN + 63) / 64;

  // layer 1 GEMM
  k_gemm128_mfma<<<gemm_blocks, 256, 0, stream>>>(x, w1hi, w1lo, nrange, Hbs1, NN);
  // fused layer-1 gather + layer-2 GEMM
  k_gather_gemm<<<gemm_blocks, 256, 0, stream>>>(nrange, csr_src, Hbs1, sc1, sh1,
                                                 w2hi, w2lo, Hbs2);
  // layer-2 gather + fused output GEMM
  k_gather128_out<<<(NN + 3) / 4, 256, 0, stream>>>(nrange, csr_src, Hbs2,
                                                    sc2, sh2, W3, H3s);
  // layer 3 aggregation
  k_gather10<<<(NN + 15) / 16, 256, 0, stream>>>(nrange, csr_src, H3s, b3, out);
}